// Round 1
// baseline (614.839 us; speedup 1.0000x reference)
//
#include <hip/hip_runtime.h>
#include <stdint.h>
#include <math.h>

#define NH 16
#define DK 64
#define S_LEN 2048
#define BB 4
#define DM 1024
#define BHT (BB*NH)      // 64
#define M_TOT (BB*S_LEN) // 8192

typedef __attribute__((ext_vector_type(8))) short short8;
typedef __attribute__((ext_vector_type(4))) float floatx4;

__device__ __forceinline__ unsigned short f2bf(float f){
  unsigned int u = __float_as_uint(f);
  u += 0x7fffu + ((u >> 16) & 1u);
  return (unsigned short)(u >> 16);
}
__device__ __forceinline__ float bf2f(unsigned short h){
  return __uint_as_float(((unsigned int)h) << 16);
}

// ---------------- cast fp32 -> bf16 ----------------
__global__ void cast_kernel(const float* __restrict__ in, unsigned short* __restrict__ out, int n){
  int i = (blockIdx.x * blockDim.x + threadIdx.x) * 4;
  if (i < n){
    float4 v = *(const float4*)(in + i);
    ushort4 u;
    u.x = f2bf(v.x); u.y = f2bf(v.y); u.z = f2bf(v.z); u.w = f2bf(v.w);
    *(ushort4*)(out + i) = u;
  }
}

// ---------------- RoPE (in-place on Q,K in [bh][s][dk]), Q scaled by 1/8 ----------------
__global__ void rope_kernel(unsigned short* __restrict__ Q, unsigned short* __restrict__ K,
                            const int* __restrict__ pos){
  int t = blockIdx.x * blockDim.x + threadIdx.x;   // BHT*S_LEN*32 threads
  int i  = t & 31;
  int s  = (t >> 5) & (S_LEN - 1);
  int bh = t >> 16;                                 // 5 + 11 bits
  float p = (float)pos[s];
  float inv = expf(-(float)i * (logf(10000.0f) / 32.0f));
  float ang = p * inv;
  float c = cosf(ang), sn = sinf(ang);
  size_t base = ((size_t)bh * S_LEN + s) * DK + 2 * i;
  {
    float xe = bf2f(Q[base]), xo = bf2f(Q[base + 1]);
    float re = xe * c - xo * sn;
    float ro = xe * sn + xo * c;
    Q[base]     = f2bf(re * 0.125f);
    Q[base + 1] = f2bf(ro * 0.125f);
  }
  {
    float xe = bf2f(K[base]), xo = bf2f(K[base + 1]);
    float re = xe * c - xo * sn;
    float ro = xe * sn + xo * c;
    K[base]     = f2bf(re);
    K[base + 1] = f2bf(ro);
  }
}

// ---------------- QKV GEMM: C[m,n] = sum_k X[m,k]*W[n,k], epilogue -> [bh][s][dk] bf16 ----------------
__global__ __launch_bounds__(256) void gemm_qkv(
    const unsigned short* __restrict__ Xb,
    const unsigned short* __restrict__ Wq,
    const unsigned short* __restrict__ Wk,
    const unsigned short* __restrict__ Wv,
    unsigned short* __restrict__ Qo,
    unsigned short* __restrict__ Ko,
    unsigned short* __restrict__ Vo)
{
  const int K = DM;
  __shared__ __align__(16) unsigned short As[128 * 32];
  __shared__ __align__(16) unsigned short Bs[128 * 32];
  int m0 = blockIdx.x * 128;
  int n0 = blockIdx.y * 128;
  int z  = blockIdx.z;
  const unsigned short* Bmat = (z == 0) ? Wq : ((z == 1) ? Wk : Wv);
  unsigned short* Out = (z == 0) ? Qo : ((z == 1) ? Ko : Vo);

  int tid = threadIdx.x;
  int wave = tid >> 6, lane = tid & 63;
  int l15 = lane & 15, quad = lane >> 4;
  int wm = (wave >> 1) * 64, wn = (wave & 1) * 64;

  floatx4 acc[4][4] = {};

  for (int k0 = 0; k0 < K; k0 += 32){
    #pragma unroll
    for (int i = 0; i < 2; i++){
      int sA = tid * 2 + i;
      int row = sA >> 2, seg = sA & 3;
      *(short8*)&As[row * 32 + seg * 8] = *(const short8*)&Xb[(size_t)(m0 + row) * K + k0 + seg * 8];
      *(short8*)&Bs[row * 32 + seg * 8] = *(const short8*)&Bmat[(size_t)(n0 + row) * K + k0 + seg * 8];
    }
    __syncthreads();
    short8 a[4], b[4];
    #pragma unroll
    for (int mi = 0; mi < 4; mi++) a[mi] = *(const short8*)&As[(wm + mi * 16 + l15) * 32 + quad * 8];
    #pragma unroll
    for (int ni = 0; ni < 4; ni++) b[ni] = *(const short8*)&Bs[(wn + ni * 16 + l15) * 32 + quad * 8];
    #pragma unroll
    for (int mi = 0; mi < 4; mi++)
      #pragma unroll
      for (int ni = 0; ni < 4; ni++)
        acc[mi][ni] = __builtin_amdgcn_mfma_f32_16x16x32_bf16(a[mi], b[ni], acc[mi][ni], 0, 0, 0);
    __syncthreads();
  }

  #pragma unroll
  for (int mi = 0; mi < 4; mi++){
    #pragma unroll
    for (int ni = 0; ni < 4; ni++){
      #pragma unroll
      for (int r = 0; r < 4; r++){
        int row = m0 + wm + mi * 16 + quad * 4 + r;
        int col = n0 + wn + ni * 16 + l15;
        int h = col >> 6, d = col & 63;
        int bb = row >> 11, s = row & (S_LEN - 1);
        Out[(((size_t)bb * NH + h) * S_LEN + s) * DK + d] = f2bf(acc[mi][ni][r]);
      }
    }
  }
}

// ---------------- Output projection GEMM: fp32 out ----------------
__global__ __launch_bounds__(256) void gemm_out(
    const unsigned short* __restrict__ Ab,
    const unsigned short* __restrict__ Wo,
    float* __restrict__ Out)
{
  const int K = DM;
  __shared__ __align__(16) unsigned short As[128 * 32];
  __shared__ __align__(16) unsigned short Bs[128 * 32];
  int m0 = blockIdx.x * 128;
  int n0 = blockIdx.y * 128;

  int tid = threadIdx.x;
  int wave = tid >> 6, lane = tid & 63;
  int l15 = lane & 15, quad = lane >> 4;
  int wm = (wave >> 1) * 64, wn = (wave & 1) * 64;

  floatx4 acc[4][4] = {};

  for (int k0 = 0; k0 < K; k0 += 32){
    #pragma unroll
    for (int i = 0; i < 2; i++){
      int sA = tid * 2 + i;
      int row = sA >> 2, seg = sA & 3;
      *(short8*)&As[row * 32 + seg * 8] = *(const short8*)&Ab[(size_t)(m0 + row) * K + k0 + seg * 8];
      *(short8*)&Bs[row * 32 + seg * 8] = *(const short8*)&Wo[(size_t)(n0 + row) * K + k0 + seg * 8];
    }
    __syncthreads();
    short8 a[4], b[4];
    #pragma unroll
    for (int mi = 0; mi < 4; mi++) a[mi] = *(const short8*)&As[(wm + mi * 16 + l15) * 32 + quad * 8];
    #pragma unroll
    for (int ni = 0; ni < 4; ni++) b[ni] = *(const short8*)&Bs[(wn + ni * 16 + l15) * 32 + quad * 8];
    #pragma unroll
    for (int mi = 0; mi < 4; mi++)
      #pragma unroll
      for (int ni = 0; ni < 4; ni++)
        acc[mi][ni] = __builtin_amdgcn_mfma_f32_16x16x32_bf16(a[mi], b[ni], acc[mi][ni], 0, 0, 0);
    __syncthreads();
  }

  #pragma unroll
  for (int mi = 0; mi < 4; mi++){
    #pragma unroll
    for (int ni = 0; ni < 4; ni++){
      #pragma unroll
      for (int r = 0; r < 4; r++){
        int row = m0 + wm + mi * 16 + quad * 4 + r;
        int col = n0 + wn + ni * 16 + l15;
        Out[(size_t)row * DM + col] = acc[mi][ni][r];
      }
    }
  }
}

// ---------------- Flash attention (causal), Q pre-scaled by 1/8 ----------------
// Q,K,V: [bh][s][dk] bf16.  Out Ao: [b][s][h][dk] bf16 (= row-major [8192,1024])
__global__ __launch_bounds__(256) void attn_kernel(
    const unsigned short* __restrict__ Qg,
    const unsigned short* __restrict__ Kg,
    const unsigned short* __restrict__ Vg,
    unsigned short* __restrict__ Ao)
{
  __shared__ __align__(16) unsigned short Ks[32 * 72];   // [kv][dk] padded
  __shared__ __align__(16) unsigned short Vt[64 * 32];   // [dk][kv]
  __shared__ __align__(16) unsigned short Ps[4][16 * 32];

  int q0 = blockIdx.x * 64;
  int bh = blockIdx.y;
  int tid = threadIdx.x, wave = tid >> 6, lane = tid & 63;
  int l15 = lane & 15, quad = lane >> 4;
  int qw = q0 + wave * 16;

  const unsigned short* Qb = Qg + (size_t)bh * S_LEN * DK;
  const unsigned short* Kb = Kg + (size_t)bh * S_LEN * DK;
  const unsigned short* Vb = Vg + (size_t)bh * S_LEN * DK;

  short8 aq0 = *(const short8*)&Qb[(qw + l15) * DK + quad * 8];
  short8 aq1 = *(const short8*)&Qb[(qw + l15) * DK + 32 + quad * 8];

  floatx4 o[4] = {};
  float mrow[4] = {-INFINITY, -INFINITY, -INFINITY, -INFINITY};
  float lrow[4] = {0.f, 0.f, 0.f, 0.f};

  int nt = (q0 + 64) / 32;
  for (int kt = 0; kt < nt; kt++){
    int kv0 = kt * 32;
    __syncthreads();
    {
      int row = tid >> 3, seg = tid & 7;
      *(short8*)&Ks[row * 72 + seg * 8] = *(const short8*)&Kb[(size_t)(kv0 + row) * DK + seg * 8];
      short8 v = *(const short8*)&Vb[(size_t)(kv0 + row) * DK + seg * 8];
      #pragma unroll
      for (int j = 0; j < 8; j++)
        Vt[(seg * 8 + j) * 32 + row] = (unsigned short)v[j];
    }
    __syncthreads();

    if (kv0 <= qw + 15){   // wave-uniform: skip fully-masked tiles
      floatx4 s0 = {}, s1 = {};
      short8 bk0 = *(const short8*)&Ks[l15 * 72 + quad * 8];
      short8 bk1 = *(const short8*)&Ks[l15 * 72 + 32 + quad * 8];
      s0 = __builtin_amdgcn_mfma_f32_16x16x32_bf16(aq0, bk0, s0, 0, 0, 0);
      s0 = __builtin_amdgcn_mfma_f32_16x16x32_bf16(aq1, bk1, s0, 0, 0, 0);
      short8 bk2 = *(const short8*)&Ks[(16 + l15) * 72 + quad * 8];
      short8 bk3 = *(const short8*)&Ks[(16 + l15) * 72 + 32 + quad * 8];
      s1 = __builtin_amdgcn_mfma_f32_16x16x32_bf16(aq0, bk2, s1, 0, 0, 0);
      s1 = __builtin_amdgcn_mfma_f32_16x16x32_bf16(aq1, bk3, s1, 0, 0, 0);

      #pragma unroll
      for (int r = 0; r < 4; r++){
        int qg = qw + quad * 4 + r;
        float v0 = (kv0 + l15 > qg)      ? -INFINITY : s0[r];
        float v1 = (kv0 + 16 + l15 > qg) ? -INFINITY : s1[r];
        float mx = fmaxf(v0, v1);
        mx = fmaxf(mx, __shfl_xor(mx, 1));
        mx = fmaxf(mx, __shfl_xor(mx, 2));
        mx = fmaxf(mx, __shfl_xor(mx, 4));
        mx = fmaxf(mx, __shfl_xor(mx, 8));
        float mnew = fmaxf(mrow[r], mx);
        float alpha = __expf(mrow[r] - mnew);
        float p0 = __expf(v0 - mnew);
        float p1 = __expf(v1 - mnew);
        float rs = p0 + p1;
        rs += __shfl_xor(rs, 1);
        rs += __shfl_xor(rs, 2);
        rs += __shfl_xor(rs, 4);
        rs += __shfl_xor(rs, 8);
        lrow[r] = lrow[r] * alpha + rs;
        mrow[r] = mnew;
        o[0][r] *= alpha; o[1][r] *= alpha; o[2][r] *= alpha; o[3][r] *= alpha;
        Ps[wave][(quad * 4 + r) * 32 + l15]      = f2bf(p0);
        Ps[wave][(quad * 4 + r) * 32 + 16 + l15] = f2bf(p1);
      }
      asm volatile("s_waitcnt lgkmcnt(0)" ::: "memory");
      short8 ap = *(const short8*)&Ps[wave][l15 * 32 + quad * 8];
      #pragma unroll
      for (int dt = 0; dt < 4; dt++){
        short8 bv = *(const short8*)&Vt[(dt * 16 + l15) * 32 + quad * 8];
        o[dt] = __builtin_amdgcn_mfma_f32_16x16x32_bf16(ap, bv, o[dt], 0, 0, 0);
      }
    }
  }

  int bq = bh >> 4, hq = bh & 15;
  #pragma unroll
  for (int dt = 0; dt < 4; dt++){
    #pragma unroll
    for (int r = 0; r < 4; r++){
      float val = o[dt][r] / lrow[r];
      int s = qw + quad * 4 + r;
      int d = dt * 16 + l15;
      Ao[(((size_t)bq * S_LEN + s) * NH + hq) * DK + d] = f2bf(val);
    }
  }
}

extern "C" void kernel_launch(void* const* d_in, const int* in_sizes, int n_in,
                              void* d_out, int out_size, void* d_ws, size_t ws_size,
                              hipStream_t stream) {
  (void)in_sizes; (void)n_in; (void)out_size; (void)ws_size;
  const float* Wq = (const float*)d_in[0];
  const float* Wk = (const float*)d_in[1];
  const float* Wv = (const float*)d_in[2];
  const float* Wo = (const float*)d_in[3];
  const float* X  = (const float*)d_in[4];
  const int* pos  = (const int*)d_in[5];
  float* out = (float*)d_out;

  char* ws = (char*)d_ws;
  const size_t MB = 1024 * 1024;
  unsigned short* Xb  = (unsigned short*)(ws);             // 16 MB
  unsigned short* Wqb = (unsigned short*)(ws + 16 * MB);   // 2 MB
  unsigned short* Wkb = (unsigned short*)(ws + 18 * MB);
  unsigned short* Wvb = (unsigned short*)(ws + 20 * MB);
  unsigned short* Wob = (unsigned short*)(ws + 22 * MB);
  unsigned short* Qb  = (unsigned short*)(ws + 24 * MB);   // 16 MB
  unsigned short* Kb  = (unsigned short*)(ws + 40 * MB);
  unsigned short* Vb  = (unsigned short*)(ws + 56 * MB);
  unsigned short* Ab  = (unsigned short*)(ws + 72 * MB);

  cast_kernel<<<8192, 256, 0, stream>>>(X,  Xb,  M_TOT * DM);
  cast_kernel<<<1024, 256, 0, stream>>>(Wq, Wqb, DM * DM);
  cast_kernel<<<1024, 256, 0, stream>>>(Wk, Wkb, DM * DM);
  cast_kernel<<<1024, 256, 0, stream>>>(Wv, Wvb, DM * DM);
  cast_kernel<<<1024, 256, 0, stream>>>(Wo, Wob, DM * DM);

  gemm_qkv<<<dim3(64, 8, 3), 256, 0, stream>>>(Xb, Wqb, Wkb, Wvb, Qb, Kb, Vb);
  rope_kernel<<<16384, 256, 0, stream>>>(Qb, Kb, pos);
  attn_kernel<<<dim3(32, 64), 256, 0, stream>>>(Qb, Kb, Vb, Ab);
  gemm_out<<<dim3(64, 8), 256, 0, stream>>>(Ab, Wob, out);
}